// Round 1
// baseline (365.810 us; speedup 1.0000x reference)
//
#include <hip/hip_runtime.h>

// Problem constants (fixed by the reference)
#define Bn   4
#define Tn   512
#define Pn   3
#define HIDn 512
#define HDn  32
#define Hn   16
#define EXPn 512
#define Sn   1024
#define Dn   96          // per-head dim = P*HD
#define LOG2E 1.44269504088896340736f

typedef __bf16 bf16_t;
typedef __bf16 bf16x8 __attribute__((ext_vector_type(8)));
typedef float  f32x4  __attribute__((ext_vector_type(4)));

// ---------------------------------------------------------------------------
// pack_qk: head-split q -> Qh [b][h][t][96] bf16; gather-expand + head-split
// k -> Kh [b][h][s][96] bf16.  (R3/R4-verified)
// ---------------------------------------------------------------------------
__global__ __launch_bounds__(192) void pack_qk(
    const float* __restrict__ q, const float* __restrict__ k,
    const int* __restrict__ outcell,
    bf16_t* __restrict__ Qh, bf16_t* __restrict__ Kh)
{
    const int bs = blockIdx.x;
    const int b = bs >> 10, s = bs & 1023;
    const int ts = (s < Tn) ? s : outcell[b * EXPn + (s - Tn)];
    const int o = threadIdx.x;            // 0..191
    const int h = o / 12, c = o % 12;     // c indexes 8-elem groups of the 96
    const int p = c >> 2, f = c & 3;
    const int src = p * HIDn + h * HDn + f * 8;

    {
        const float* krow = k + (size_t)(b * Tn + ts) * (Pn * HIDn);
        const float4* s4 = (const float4*)(krow + src);
        float4 f0 = s4[0], f1 = s4[1];
        bf16_t o8[8] = {(bf16_t)f0.x, (bf16_t)f0.y, (bf16_t)f0.z, (bf16_t)f0.w,
                        (bf16_t)f1.x, (bf16_t)f1.y, (bf16_t)f1.z, (bf16_t)f1.w};
        *(uint4*)&Kh[(((size_t)b * Hn + h) * Sn + s) * Dn + c * 8] = *(uint4*)o8;
    }
    if (s < Tn) {
        const float* qrow = q + (size_t)(b * Tn + s) * (Pn * HIDn);
        const float4* s4 = (const float4*)(qrow + src);
        float4 f0 = s4[0], f1 = s4[1];
        bf16_t o8[8] = {(bf16_t)f0.x, (bf16_t)f0.y, (bf16_t)f0.z, (bf16_t)f0.w,
                        (bf16_t)f1.x, (bf16_t)f1.y, (bf16_t)f1.z, (bf16_t)f1.w};
        *(uint4*)&Qh[(((size_t)b * Hn + h) * Tn + s) * Dn + c * 8] = *(uint4*)o8;
    }
}

// ---------------------------------------------------------------------------
// pack_v: gather-expand + head-split + TRANSPOSE v -> Vt [b][h][96][S] bf16.
// (R3/R4-verified)
// ---------------------------------------------------------------------------
__global__ __launch_bounds__(256) void pack_v(
    const float* __restrict__ v, const int* __restrict__ outcell,
    bf16_t* __restrict__ Vt)
{
    const int blk = blockIdx.x;
    const int bh = blk >> 4, s0 = (blk & 15) << 6;
    const int b = bh >> 4, h = bh & 15;
    __shared__ float tile[64 * 108];
    __shared__ int ts_sh[64];
    if (threadIdx.x < 64) {
        const int s = s0 + threadIdx.x;
        ts_sh[threadIdx.x] = (s < Tn) ? s : outcell[b * EXPn + (s - Tn)];
    }
    __syncthreads();
    for (int u = threadIdx.x; u < 64 * 24; u += 256) {
        const int sl = u / 24, c = u % 24;
        const int p = c >> 3, f = c & 7;
        float4 val = *(const float4*)&v[(size_t)(b * Tn + ts_sh[sl]) * (Pn * HIDn)
                                        + p * HIDn + h * HDn + f * 4];
        *(float4*)&tile[sl * 108 + c * 4] = val;
    }
    __syncthreads();
    for (int e = threadIdx.x; e < 96 * 8; e += 256) {
        const int d = e >> 3, g = e & 7;
        bf16_t o8[8];
#pragma unroll
        for (int j = 0; j < 8; ++j) o8[j] = (bf16_t)tile[(g * 8 + j) * 108 + d];
        *(uint4*)&Vt[((size_t)bh * Dn + d) * Sn + s0 + g * 8] = *(uint4*)o8;
    }
}

// ---------------------------------------------------------------------------
// pack_w: out_proj_weight fp32 [o][d] -> bf16 [o][d]  (verified)
// ---------------------------------------------------------------------------
__global__ __launch_bounds__(256) void pack_w(
    const float* __restrict__ W, bf16_t* __restrict__ Wb)
{
    const int i = blockIdx.x * 256 + threadIdx.x;
    float4 f0 = *(const float4*)&W[i * 8];
    float4 f1 = *(const float4*)&W[i * 8 + 4];
    bf16_t o8[8] = {(bf16_t)f0.x, (bf16_t)f0.y, (bf16_t)f0.z, (bf16_t)f0.w,
                    (bf16_t)f1.x, (bf16_t)f1.y, (bf16_t)f1.z, (bf16_t)f1.w};
    *(uint4*)&Wb[i * 8] = *(uint4*)o8;
}

// ---------------------------------------------------------------------------
// attn_kernel R6: 512 threads / 8 waves per block.  Waves are (wt, sg):
// wt in [0,4) owns 16 t-rows (as before), sg in {0,1} owns HALF the S range
// (8 chunks of 64 instead of 16).  Rationale: R5 counters showed the kernel
// is latency-bound with a GRID-SIZE occupancy cap (512 blocks x 4 waves =
// 2 blocks/CU = 8 waves/CU = 22% occ, MfmaUtil 4%).  The s-split doubles
// resident waves to 16/CU and halves each wave's serial chunk chain.
// Partial (m, l, O) merged across sg via LDS at the end (one extra barrier
// pair + 24 floats/lane round-trip, once per block).  Arithmetic inside the
// chunk loop is IDENTICAL to R5 (register dbuf of bias/lw kept).
// ---------------------------------------------------------------------------
__global__ __launch_bounds__(512, 4) void attn_kernel(
    const bf16_t* __restrict__ Qh, const bf16_t* __restrict__ Kh,
    const bf16_t* __restrict__ Vt, const float* __restrict__ bias,
    const float* __restrict__ lw, float* __restrict__ attn_out,
    float* __restrict__ sumsq)
{
    const int h  = blockIdx.x;
    const int b  = blockIdx.y >> 3;
    const int t0 = (blockIdx.y & 7) << 6;
    const int tid = threadIdx.x;
    const int wv  = tid >> 6;             // 0..7
    const int wt  = wv & 3;               // t-subtile (16 rows)
    const int sg  = wv >> 2;              // s-half: 0 -> [0,512), 1 -> [512,1024)
    const int lane = tid & 63;
    const int l16 = lane & 15;
    const int quad = lane >> 4;

    __shared__ bf16_t Ps[8][16 * 72];     // per-wave P-transpose buffer
    __shared__ float  Cm[4][64][8];       // combine: m[0..3], l[0..3] per lane
    __shared__ float  Co[4][64][24];      // combine: Oacc partials per lane

    const size_t bh = (size_t)b * Hn + h;
    const int tb = t0 + wt * 16;          // this wave's first t-row
    const int sbase = sg * (Sn / 2);      // this wave's s-range start

    // Q A-fragments held in regs all kernel
    bf16x8 qf[3];
    {
        const bf16_t* qb = Qh + (bh * Tn + tb + l16) * Dn + quad * 8;
#pragma unroll
        for (int ks = 0; ks < 3; ++ks) qf[ks] = *(const bf16x8*)(qb + ks * 32);
    }

    const bf16_t* kbase = Kh + (bh * Sn + l16) * Dn + quad * 8;
    const bf16_t* vbase = Vt + (bh * Dn + l16) * Sn + quad * 8;
    const float*  bbase = bias + ((bh * Tn + tb + quad * 4)) * (size_t)Sn + l16;
    const float*  lbase = lw + (((size_t)b * Tn + tb + quad * 4)) * Sn + l16;

    f32x4 Oacc[6];
#pragma unroll
    for (int i = 0; i < 6; ++i) Oacc[i] = f32x4{0.f, 0.f, 0.f, 0.f};
    float mrow[4], lrow[4];
#pragma unroll
    for (int r = 0; r < 4; ++r) { mrow[r] = -3.0e38f; lrow[r] = 0.f; }

    // ---- prologue: bias/lw for this wave's chunk 0 into the "current" set
    float BRc[16], LRc[16], BRn[16], LRn[16];
#pragma unroll
    for (int ct = 0; ct < 4; ++ct)
#pragma unroll
        for (int r = 0; r < 4; ++r) {
            BRc[ct * 4 + r] = bbase[(size_t)r * Sn + sbase + ct * 16];
            LRc[ct * 4 + r] = lbase[(size_t)r * Sn + sbase + ct * 16];
        }

    for (int s0i = 0; s0i < Sn / 2; s0i += 64) {
        const int s0 = sbase + s0i;
        // ---- issue current chunk's K B-frags (L2-resident after 1st block)
        bf16x8 kf[4][3];
#pragma unroll
        for (int ct = 0; ct < 4; ++ct)
#pragma unroll
            for (int ks = 0; ks < 3; ++ks)
                kf[ct][ks] = *(const bf16x8*)(kbase + (size_t)(s0 + ct * 16) * Dn + ks * 32);

        // ---- issue NEXT chunk's bias/lw (HBM stream; consumed next iter)
        const int s0n = sbase + ((s0i + 64 < Sn / 2) ? (s0i + 64) : 0);  // wrap: harmless
#pragma unroll
        for (int ct = 0; ct < 4; ++ct)
#pragma unroll
            for (int r = 0; r < 4; ++r) {
                BRn[ct * 4 + r] = bbase[(size_t)r * Sn + s0n + ct * 16];
                LRn[ct * 4 + r] = lbase[(size_t)r * Sn + s0n + ct * 16];
            }

        // ---- QK^T: 16 rows x 64 cols
        f32x4 sc[4];
#pragma unroll
        for (int ct = 0; ct < 4; ++ct) {
            f32x4 acc = f32x4{0.f, 0.f, 0.f, 0.f};
#pragma unroll
            for (int ks = 0; ks < 3; ++ks)
                acc = __builtin_amdgcn_mfma_f32_16x16x32_bf16(qf[ks], kf[ct][ks], acc, 0, 0, 0);
            sc[ct] = acc;
        }

        // ---- + bias (regs loaded LAST chunk), lw-cutoff mask, chunk row-max
        float cmax[4] = {-3.0e38f, -3.0e38f, -3.0e38f, -3.0e38f};
#pragma unroll
        for (int ct = 0; ct < 4; ++ct) {
#pragma unroll
            for (int r = 0; r < 4; ++r) {
                float wval = sc[ct][r] + BRc[ct * 4 + r];
                wval = (LRc[ct * 4 + r] <= 1e-5f) ? -3.0e38f : wval;
                sc[ct][r] = wval;
                cmax[r] = fmaxf(cmax[r], wval);
            }
        }
#pragma unroll
        for (int off = 1; off < 16; off <<= 1)
#pragma unroll
            for (int r = 0; r < 4; ++r)
                cmax[r] = fmaxf(cmax[r], __shfl_xor(cmax[r], off));

        // ---- online-softmax rescale
        float scl[4];
#pragma unroll
        for (int r = 0; r < 4; ++r) {
            const float mnew = fmaxf(mrow[r], cmax[r]);
            scl[r] = exp2f((mrow[r] - mnew) * LOG2E);
            mrow[r] = mnew;
            lrow[r] *= scl[r];
        }
#pragma unroll
        for (int dt = 0; dt < 6; ++dt)
#pragma unroll
            for (int r = 0; r < 4; ++r) Oacc[dt][r] *= scl[r];

        // ---- p = exp(w-m); l += p; stage (p*lw) bf16 in this wave's Ps
        float lsum[4] = {0.f, 0.f, 0.f, 0.f};
#pragma unroll
        for (int ct = 0; ct < 4; ++ct) {
#pragma unroll
            for (int r = 0; r < 4; ++r) {
                const float pe = exp2f((sc[ct][r] - mrow[r]) * LOG2E);
                lsum[r] += pe;
                Ps[wv][(quad * 4 + r) * 72 + ct * 16 + l16] = (bf16_t)(pe * LRc[ct * 4 + r]);
            }
        }
#pragma unroll
        for (int off = 1; off < 16; off <<= 1)
#pragma unroll
            for (int r = 0; r < 4; ++r) lsum[r] += __shfl_xor(lsum[r], off);
#pragma unroll
        for (int r = 0; r < 4; ++r) lrow[r] += lsum[r];

        // ---- PV: Oacc[dt] += P(16x64) * V^T-frags (L2; loads pipeline)
        bf16x8 pa[2];
#pragma unroll
        for (int ks = 0; ks < 2; ++ks)
            pa[ks] = *(const bf16x8*)&Ps[wv][l16 * 72 + ks * 32 + quad * 8];
#pragma unroll
        for (int dt = 0; dt < 6; ++dt) {
#pragma unroll
            for (int ks = 0; ks < 2; ++ks) {
                bf16x8 vf = *(const bf16x8*)(vbase + (size_t)(dt * 16) * Sn + s0 + ks * 32);
                Oacc[dt] = __builtin_amdgcn_mfma_f32_16x16x32_bf16(pa[ks], vf, Oacc[dt], 0, 0, 0);
            }
        }

        // ---- rotate bias/lw double-buffer
#pragma unroll
        for (int i = 0; i < 16; ++i) { BRc[i] = BRn[i]; LRc[i] = LRn[i]; }
    }

    // ---- cross-sg combine: sg=1 publishes partial (m,l,O); sg=0 merges
    __syncthreads();
    if (sg == 1) {
#pragma unroll
        for (int r = 0; r < 4; ++r) {
            Cm[wt][lane][r]     = mrow[r];
            Cm[wt][lane][4 + r] = lrow[r];
        }
#pragma unroll
        for (int dt = 0; dt < 6; ++dt)
#pragma unroll
            for (int r = 0; r < 4; ++r) Co[wt][lane][dt * 4 + r] = Oacc[dt][r];
    }
    __syncthreads();
    if (sg == 1) return;

    {
        float a0[4], a1[4];
#pragma unroll
        for (int r = 0; r < 4; ++r) {
            const float m1 = Cm[wt][lane][r];
            const float l1 = Cm[wt][lane][4 + r];
            const float mn = fmaxf(mrow[r], m1);
            a0[r] = exp2f((mrow[r] - mn) * LOG2E);
            a1[r] = exp2f((m1 - mn) * LOG2E);
            mrow[r] = mn;
            lrow[r] = lrow[r] * a0[r] + l1 * a1[r];
        }
#pragma unroll
        for (int dt = 0; dt < 6; ++dt)
#pragma unroll
            for (int r = 0; r < 4; ++r)
                Oacc[dt][r] = Oacc[dt][r] * a0[r] + Co[wt][lane][dt * 4 + r] * a1[r];
    }

    // ---- finalize: O /= l, scatter to (B,T,P,HID), sumsq atomics
    float invl[4];
#pragma unroll
    for (int r = 0; r < 4; ++r) invl[r] = 1.0f / lrow[r];
    float ss[4] = {0.f, 0.f, 0.f, 0.f};
#pragma unroll
    for (int dt = 0; dt < 6; ++dt) {
        const int d = dt * 16 + l16;
        const int p = d >> 5, hd = d & 31;
#pragma unroll
        for (int r = 0; r < 4; ++r) {
            const int t = tb + quad * 4 + r;
            const float o = Oacc[dt][r] * invl[r];
            attn_out[(((size_t)b * Tn + t) * Pn + p) * HIDn + h * HDn + hd] = o;
            ss[r] += o * o;
        }
    }
#pragma unroll
    for (int off = 1; off < 16; off <<= 1)
#pragma unroll
        for (int r = 0; r < 4; ++r) ss[r] += __shfl_xor(ss[r], off);
    if (l16 == 0) {
#pragma unroll
        for (int r = 0; r < 4; ++r)
            atomicAdd(&sumsq[b * Tn + tb + quad * 4 + r], ss[r]);
    }
}

// ---------------------------------------------------------------------------
// out_gemm (LN fused): xln = attn * lnw[k] * rsqrt(sumsq[bt]/512+eps) during
// the LDS stage; 64x64 dbuf MFMA.  (R4-verified)
// ---------------------------------------------------------------------------
__global__ __launch_bounds__(256, 2) void out_gemm(
    const float* __restrict__ attn, const float* __restrict__ sumsq,
    const float* __restrict__ lnwg, const bf16_t* __restrict__ Bw,
    float* __restrict__ out)
{
    const int n0 = blockIdx.x * 64;
    const int m0 = blockIdx.y * 64;
    const int tid = threadIdx.x;
    const int wv = tid >> 6, lane = tid & 63, l16 = lane & 15, quad = lane >> 4;
    __shared__ float lnw_s[HIDn];
    __shared__ float inv_s[64];
    __shared__ bf16_t As[2][64 * 72];
    __shared__ bf16_t Bs[2][64 * 72];

    for (int i = tid; i < HIDn; i += 256) lnw_s[i] = lnwg[i];
    if (tid < 64)
        inv_s[tid] = rsqrtf(sumsq[(m0 + tid) / 3] * (1.0f / HIDn) + 1e-3f);
    __syncthreads();

    const int rowA = tid >> 3, cA = tid & 7;
    const float inv0 = inv_s[rowA], inv1 = inv_s[rowA + 32];

    auto loadT = [&](int k0, float4 (&AF)[2][2], uint4 (&BR)[2], float4 (&LF)[2]) {
        LF[0] = *(const float4*)&lnw_s[k0 + cA * 8];
        LF[1] = *(const float4*)&lnw_s[k0 + cA * 8 + 4];
        AF[0][0] = *(const float4*)&attn[(size_t)(m0 + rowA) * HIDn + k0 + cA * 8];
        AF[0][1] = *(const float4*)&attn[(size_t)(m0 + rowA) * HIDn + k0 + cA * 8 + 4];
        AF[1][0] = *(const float4*)&attn[(size_t)(m0 + rowA + 32) * HIDn + k0 + cA * 8];
        AF[1][1] = *(const float4*)&attn[(size_t)(m0 + rowA + 32) * HIDn + k0 + cA * 8 + 4];
        BR[0] = *(const uint4*)&Bw[(size_t)(n0 + rowA) * HIDn + k0 + cA * 8];
        BR[1] = *(const uint4*)&Bw[(size_t)(n0 + rowA + 32) * HIDn + k0 + cA * 8];
    };
    auto storeT = [&](int buf, float4 (&AF)[2][2], uint4 (&BR)[2], float4 (&LF)[2]) {
#pragma unroll
        for (int j = 0; j < 2; ++j) {
            const float iv = j ? inv1 : inv0;
            bf16_t a8[8] = {(bf16_t)(AF[j][0].x * LF[0].x * iv), (bf16_t)(AF[j][0].y * LF[0].y * iv),
                            (bf16_t)(AF[j][0].z * LF[0].z * iv), (bf16_t)(AF[j][0].w * LF[0].w * iv),
                            (bf16_t)(AF[j][1].x * LF[1].x * iv), (bf16_t)(AF[j][1].y * LF[1].y * iv),
                            (bf16_t)(AF[j][1].z * LF[1].z * iv), (bf16_t)(AF[j][1].w * LF[1].w * iv)};
            *(uint4*)&As[buf][(rowA + j * 32) * 72 + cA * 8] = *(uint4*)a8;
            *(uint4*)&Bs[buf][(rowA + j * 32) * 72 + cA * 8] = BR[j];
        }
    };

    f32x4 acc[4];
#pragma unroll
    for (int i = 0; i < 4; ++i) acc[i] = f32x4{0.f, 0.f, 0.f, 0.f};

    float4 af0[2][2], af1[2][2], lf0[2], lf1[2];
    uint4 br0[2], br1[2];
    loadT(0, af0, br0, lf0);
    storeT(0, af0, br0, lf0);
    __syncthreads();

    auto compute = [&](int buf) {
#pragma unroll
        for (int ks = 0; ks < 2; ++ks) {
            bf16x8 a = *(const bf16x8*)&As[buf][(wv * 16 + l16) * 72 + ks * 32 + quad * 8];
#pragma unroll
            for (int nt = 0; nt < 4; ++nt) {
                bf16x8 bb = *(const bf16x8*)&Bs[buf][(nt * 16 + l16) * 72 + ks * 32 + quad * 8];
                acc[nt] = __builtin_amdgcn_mfma_f32_16x16x32_bf16(a, bb, acc[nt], 0, 0, 0);
            }
        }
    };

    for (int it = 0; it < 8; it += 2) {
        loadT((it + 1) * 64, af1, br1, lf1);
        compute(0);
        storeT(1, af1, br1, lf1);
        __syncthreads();
        const bool pf = (it + 2) < 8;
        if (pf) loadT((it + 2) * 64, af0, br0, lf0);
        compute(1);
        if (pf) storeT(0, af0, br0, lf0);
        __syncthreads();
    }
#pragma unroll
    for (int nt = 0; nt < 4; ++nt)
#pragma unroll
        for (int r = 0; r < 4; ++r) {
            const int m = m0 + wv * 16 + quad * 4 + r;
            const int n = n0 + nt * 16 + l16;
            out[(size_t)m * HIDn + n] = acc[nt][r];
        }
}

// ---------------------------------------------------------------------------
// Workspace: Qh@0 (6291456) | Kh@6291456 (12582912) | Vt@18874368 (12582912) |
// attn@31457280 (12582912) | Wb@44040192 (524288) | sumsq@44564480 (8192)
// ---------------------------------------------------------------------------
extern "C" void kernel_launch(void* const* d_in, const int* in_sizes, int n_in,
                              void* d_out, int out_size, void* d_ws, size_t ws_size,
                              hipStream_t stream)
{
    const float* q    = (const float*)d_in[0];
    const float* k    = (const float*)d_in[1];
    const float* v    = (const float*)d_in[2];
    const float* bias = (const float*)d_in[3];
    const int*   outcell = (const int*)d_in[5];
    const float* lw   = (const float*)d_in[6];
    const float* W    = (const float*)d_in[8];
    const float* lnw  = (const float*)d_in[9];
    float* out = (float*)d_out;

    char* ws = (char*)d_ws;
    bf16_t* Qh   = (bf16_t*)(ws);
    bf16_t* Kh   = (bf16_t*)(ws + 6291456);
    bf16_t* Vt   = (bf16_t*)(ws + 18874368);
    float*  attn = (float*)(ws + 31457280);
    bf16_t* Wb   = (bf16_t*)(ws + 44040192);
    float*  sumsq = (float*)(ws + 44564480);

    hipMemsetAsync(sumsq, 0, (Bn * Tn) * sizeof(float), stream);
    pack_qk<<<dim3(Bn * Sn), 192, 0, stream>>>(q, k, outcell, Qh, Kh);
    pack_v<<<dim3(Bn * Hn * 16), 256, 0, stream>>>(v, outcell, Vt);
    pack_w<<<dim3((HIDn * HIDn) / (256 * 8)), 256, 0, stream>>>(W, Wb);
    attn_kernel<<<dim3(Hn, Bn * (Tn / 64)), 512, 0, stream>>>(Qh, Kh, Vt, bias, lw, attn, sumsq);
    out_gemm<<<dim3(HIDn / 64, (Bn * Tn * Pn) / 64), 256, 0, stream>>>(attn, sumsq, lnw, Wb, out);
}

// Round 2
// 338.333 us; speedup vs baseline: 1.0812x; 1.0812x over previous
//
#include <hip/hip_runtime.h>

// Problem constants (fixed by the reference)
#define Bn   4
#define Tn   512
#define Pn   3
#define HIDn 512
#define HDn  32
#define Hn   16
#define EXPn 512
#define Sn   1024
#define Dn   96          // per-head dim = P*HD
#define LOG2E 1.44269504088896340736f

typedef __bf16 bf16_t;
typedef __bf16 bf16x8 __attribute__((ext_vector_type(8)));
typedef float  f32x4  __attribute__((ext_vector_type(4)));

// ---------------------------------------------------------------------------
// pack_qk: head-split q -> Qh [b][h][t][96] bf16; gather-expand + head-split
// k -> Kh [b][h][s][96] bf16.  (R3/R4-verified)
// ---------------------------------------------------------------------------
__global__ __launch_bounds__(192) void pack_qk(
    const float* __restrict__ q, const float* __restrict__ k,
    const int* __restrict__ outcell,
    bf16_t* __restrict__ Qh, bf16_t* __restrict__ Kh)
{
    const int bs = blockIdx.x;
    const int b = bs >> 10, s = bs & 1023;
    const int ts = (s < Tn) ? s : outcell[b * EXPn + (s - Tn)];
    const int o = threadIdx.x;            // 0..191
    const int h = o / 12, c = o % 12;     // c indexes 8-elem groups of the 96
    const int p = c >> 2, f = c & 3;
    const int src = p * HIDn + h * HDn + f * 8;

    {
        const float* krow = k + (size_t)(b * Tn + ts) * (Pn * HIDn);
        const float4* s4 = (const float4*)(krow + src);
        float4 f0 = s4[0], f1 = s4[1];
        bf16_t o8[8] = {(bf16_t)f0.x, (bf16_t)f0.y, (bf16_t)f0.z, (bf16_t)f0.w,
                        (bf16_t)f1.x, (bf16_t)f1.y, (bf16_t)f1.z, (bf16_t)f1.w};
        *(uint4*)&Kh[(((size_t)b * Hn + h) * Sn + s) * Dn + c * 8] = *(uint4*)o8;
    }
    if (s < Tn) {
        const float* qrow = q + (size_t)(b * Tn + s) * (Pn * HIDn);
        const float4* s4 = (const float4*)(qrow + src);
        float4 f0 = s4[0], f1 = s4[1];
        bf16_t o8[8] = {(bf16_t)f0.x, (bf16_t)f0.y, (bf16_t)f0.z, (bf16_t)f0.w,
                        (bf16_t)f1.x, (bf16_t)f1.y, (bf16_t)f1.z, (bf16_t)f1.w};
        *(uint4*)&Qh[(((size_t)b * Hn + h) * Tn + s) * Dn + c * 8] = *(uint4*)o8;
    }
}

// ---------------------------------------------------------------------------
// pack_v: gather-expand + head-split + TRANSPOSE v -> Vt [b][h][96][S] bf16.
// (R3/R4-verified)
// ---------------------------------------------------------------------------
__global__ __launch_bounds__(256) void pack_v(
    const float* __restrict__ v, const int* __restrict__ outcell,
    bf16_t* __restrict__ Vt)
{
    const int blk = blockIdx.x;
    const int bh = blk >> 4, s0 = (blk & 15) << 6;
    const int b = bh >> 4, h = bh & 15;
    __shared__ float tile[64 * 108];
    __shared__ int ts_sh[64];
    if (threadIdx.x < 64) {
        const int s = s0 + threadIdx.x;
        ts_sh[threadIdx.x] = (s < Tn) ? s : outcell[b * EXPn + (s - Tn)];
    }
    __syncthreads();
    for (int u = threadIdx.x; u < 64 * 24; u += 256) {
        const int sl = u / 24, c = u % 24;
        const int p = c >> 3, f = c & 7;
        float4 val = *(const float4*)&v[(size_t)(b * Tn + ts_sh[sl]) * (Pn * HIDn)
                                        + p * HIDn + h * HDn + f * 4];
        *(float4*)&tile[sl * 108 + c * 4] = val;
    }
    __syncthreads();
    for (int e = threadIdx.x; e < 96 * 8; e += 256) {
        const int d = e >> 3, g = e & 7;
        bf16_t o8[8];
#pragma unroll
        for (int j = 0; j < 8; ++j) o8[j] = (bf16_t)tile[(g * 8 + j) * 108 + d];
        *(uint4*)&Vt[((size_t)bh * Dn + d) * Sn + s0 + g * 8] = *(uint4*)o8;
    }
}

// ---------------------------------------------------------------------------
// pack_w: out_proj_weight fp32 [o][d] -> bf16 [o][d]  (verified)
// ---------------------------------------------------------------------------
__global__ __launch_bounds__(256) void pack_w(
    const float* __restrict__ W, bf16_t* __restrict__ Wb)
{
    const int i = blockIdx.x * 256 + threadIdx.x;
    float4 f0 = *(const float4*)&W[i * 8];
    float4 f1 = *(const float4*)&W[i * 8 + 4];
    bf16_t o8[8] = {(bf16_t)f0.x, (bf16_t)f0.y, (bf16_t)f0.z, (bf16_t)f0.w,
                    (bf16_t)f1.x, (bf16_t)f1.y, (bf16_t)f1.z, (bf16_t)f1.w};
    *(uint4*)&Wb[i * 8] = *(uint4*)o8;
}

// ---------------------------------------------------------------------------
// attn_kernel R7: back to the R5 4-wave structure (R6's 8-wave s-split hit a
// 64-VGPR cap and spilled: WRITE_SIZE +14MB, slower).  R5's real bottleneck:
// the bias/lw "register double-buffer" never existed -- at 92 VGPRs the
// compiler serialized the 32 scalar loads/chunk into small batches with
// waits (avg in-flight ~1.6KB/CU vs the ~9KB Little's-law needs -> 1.1 TB/s
// on a stream-once 134MB tensor).  R7 streams bias/lw with ZERO VGPR cost:
// 8x global_load_lds width-16 (1KB/instr) per chunk into per-wave LDS tiles
// [16][64] f32, double-buffered; prefetch of chunk i+1 issued during chunk i.
// Explicit s_waitcnt vmcnt(0) + memory clobber at chunk top orders the
// prefetch->ds_read dependency (compiler does not model it).  Lanes read
// their 16 scalars per array from LDS (4-way bank conflict, ~1.58x on those
// reads -- cheap).  Arithmetic identical to R5 (PASS).
// LDS: Bt 32KB + Lt 32KB + Ps 9KB = 74.75KB -> 2 blocks/CU.
// ---------------------------------------------------------------------------
__global__ __launch_bounds__(256, 2) void attn_kernel(
    const bf16_t* __restrict__ Qh, const bf16_t* __restrict__ Kh,
    const bf16_t* __restrict__ Vt, const float* __restrict__ bias,
    const float* __restrict__ lw, float* __restrict__ attn_out,
    float* __restrict__ sumsq)
{
    const int h  = blockIdx.x;
    const int b  = blockIdx.y >> 3;
    const int t0 = (blockIdx.y & 7) << 6;
    const int tid = threadIdx.x;
    const int wv  = tid >> 6;
    const int lane = tid & 63;
    const int l16 = lane & 15;
    const int quad = lane >> 4;

    __shared__ float  Bt[4][2][16 * 64];  // per-wave bias tile, double-buffered
    __shared__ float  Lt[4][2][16 * 64];  // per-wave lw tile, double-buffered
    __shared__ bf16_t Ps[4][16 * 72];     // per-wave P-transpose buffer

    const size_t bh = (size_t)b * Hn + h;
    const int tb = t0 + wv * 16;          // this wave's first t-row

    // Q A-fragments held in regs all kernel
    bf16x8 qf[3];
    {
        const bf16_t* qb = Qh + (bh * Tn + tb + l16) * Dn + quad * 8;
#pragma unroll
        for (int ks = 0; ks < 3; ++ks) qf[ks] = *(const bf16x8*)(qb + ks * 32);
    }

    const bf16_t* kbase = Kh + (bh * Sn + l16) * Dn + quad * 8;
    const bf16_t* vbase = Vt + (bh * Dn + l16) * Sn + quad * 8;

    // per-lane global sources for the cooperative bias/lw -> LDS prefetch:
    // lane covers row (kk*4 + lane>>4), cols (lane&15)*4 .. +3 of the 16x64 tile
    const int prow = lane >> 4;
    const int pcol = (lane & 15) * 4;
    const float* gb0 = bias + (bh * Tn + tb + prow) * (size_t)Sn + pcol;
    const float* gl0 = lw + ((size_t)b * Tn + tb + prow) * Sn + pcol;

    auto prefetch = [&](int s0, int buf) {
#pragma unroll
        for (int kk = 0; kk < 4; ++kk) {
            __builtin_amdgcn_global_load_lds(
                (const __attribute__((address_space(1))) void*)(gb0 + (size_t)kk * 4 * Sn + s0),
                (__attribute__((address_space(3))) void*)&Bt[wv][buf][kk * 256], 16, 0, 0);
            __builtin_amdgcn_global_load_lds(
                (const __attribute__((address_space(1))) void*)(gl0 + (size_t)kk * 4 * Sn + s0),
                (__attribute__((address_space(3))) void*)&Lt[wv][buf][kk * 256], 16, 0, 0);
        }
    };

    f32x4 Oacc[6];
#pragma unroll
    for (int i = 0; i < 6; ++i) Oacc[i] = f32x4{0.f, 0.f, 0.f, 0.f};
    float mrow[4], lrow[4];
#pragma unroll
    for (int r = 0; r < 4; ++r) { mrow[r] = -3.0e38f; lrow[r] = 0.f; }

    // prologue: chunk 0's tiles
    prefetch(0, 0);

    for (int s0 = 0, cur = 0; s0 < Sn; s0 += 64, cur ^= 1) {
        // ---- wait for this chunk's LDS tiles (issued last chunk; ~landed)
        asm volatile("s_waitcnt vmcnt(0)" ::: "memory");

        // ---- pull this chunk's bias/lw scalars from LDS (4-way bank conflict)
        float BR[16], LR[16];
        {
            const float* bt = &Bt[wv][cur][quad * 4 * 64 + l16];
            const float* lt = &Lt[wv][cur][quad * 4 * 64 + l16];
#pragma unroll
            for (int ct = 0; ct < 4; ++ct)
#pragma unroll
                for (int r = 0; r < 4; ++r) {
                    BR[ct * 4 + r] = bt[r * 64 + ct * 16];
                    LR[ct * 4 + r] = lt[r * 64 + ct * 16];
                }
        }

        // ---- issue current chunk's K B-frags (L2/L3-resident)
        bf16x8 kf[4][3];
#pragma unroll
        for (int ct = 0; ct < 4; ++ct)
#pragma unroll
            for (int ks = 0; ks < 3; ++ks)
                kf[ct][ks] = *(const bf16x8*)(kbase + (size_t)(s0 + ct * 16) * Dn + ks * 32);

        // ---- issue NEXT chunk's bias/lw prefetch (8 wide async lds-loads)
        if (s0 + 64 < Sn) prefetch(s0 + 64, cur ^ 1);

        // ---- QK^T: 16 rows x 64 cols
        f32x4 sc[4];
#pragma unroll
        for (int ct = 0; ct < 4; ++ct) {
            f32x4 acc = f32x4{0.f, 0.f, 0.f, 0.f};
#pragma unroll
            for (int ks = 0; ks < 3; ++ks)
                acc = __builtin_amdgcn_mfma_f32_16x16x32_bf16(qf[ks], kf[ct][ks], acc, 0, 0, 0);
            sc[ct] = acc;
        }

        // ---- + bias, lw-cutoff mask, chunk row-max
        float cmax[4] = {-3.0e38f, -3.0e38f, -3.0e38f, -3.0e38f};
#pragma unroll
        for (int ct = 0; ct < 4; ++ct) {
#pragma unroll
            for (int r = 0; r < 4; ++r) {
                float wval = sc[ct][r] + BR[ct * 4 + r];
                wval = (LR[ct * 4 + r] <= 1e-5f) ? -3.0e38f : wval;
                sc[ct][r] = wval;
                cmax[r] = fmaxf(cmax[r], wval);
            }
        }
#pragma unroll
        for (int off = 1; off < 16; off <<= 1)
#pragma unroll
            for (int r = 0; r < 4; ++r)
                cmax[r] = fmaxf(cmax[r], __shfl_xor(cmax[r], off));

        // ---- online-softmax rescale
        float scl[4];
#pragma unroll
        for (int r = 0; r < 4; ++r) {
            const float mnew = fmaxf(mrow[r], cmax[r]);
            scl[r] = exp2f((mrow[r] - mnew) * LOG2E);
            mrow[r] = mnew;
            lrow[r] *= scl[r];
        }
#pragma unroll
        for (int dt = 0; dt < 6; ++dt)
#pragma unroll
            for (int r = 0; r < 4; ++r) Oacc[dt][r] *= scl[r];

        // ---- p = exp(w-m); l += p; stage (p*lw) bf16 in this wave's Ps
        float lsum[4] = {0.f, 0.f, 0.f, 0.f};
#pragma unroll
        for (int ct = 0; ct < 4; ++ct) {
#pragma unroll
            for (int r = 0; r < 4; ++r) {
                const float pe = exp2f((sc[ct][r] - mrow[r]) * LOG2E);
                lsum[r] += pe;
                Ps[wv][(quad * 4 + r) * 72 + ct * 16 + l16] = (bf16_t)(pe * LR[ct * 4 + r]);
            }
        }
#pragma unroll
        for (int off = 1; off < 16; off <<= 1)
#pragma unroll
            for (int r = 0; r < 4; ++r) lsum[r] += __shfl_xor(lsum[r], off);
#pragma unroll
        for (int r = 0; r < 4; ++r) lrow[r] += lsum[r];

        // ---- PV: Oacc[dt] += P(16x64) * V^T-frags (L2; loads pipeline)
        bf16x8 pa[2];
#pragma unroll
        for (int ks = 0; ks < 2; ++ks)
            pa[ks] = *(const bf16x8*)&Ps[wv][l16 * 72 + ks * 32 + quad * 8];
#pragma unroll
        for (int dt = 0; dt < 6; ++dt) {
#pragma unroll
            for (int ks = 0; ks < 2; ++ks) {
                bf16x8 vf = *(const bf16x8*)(vbase + (size_t)(dt * 16) * Sn + s0 + ks * 32);
                Oacc[dt] = __builtin_amdgcn_mfma_f32_16x16x32_bf16(pa[ks], vf, Oacc[dt], 0, 0, 0);
            }
        }
    }

    // ---- finalize: O /= l, scatter to (B,T,P,HID), sumsq atomics
    float invl[4];
#pragma unroll
    for (int r = 0; r < 4; ++r) invl[r] = 1.0f / lrow[r];
    float ss[4] = {0.f, 0.f, 0.f, 0.f};
#pragma unroll
    for (int dt = 0; dt < 6; ++dt) {
        const int d = dt * 16 + l16;
        const int p = d >> 5, hd = d & 31;
#pragma unroll
        for (int r = 0; r < 4; ++r) {
            const int t = tb + quad * 4 + r;
            const float o = Oacc[dt][r] * invl[r];
            attn_out[(((size_t)b * Tn + t) * Pn + p) * HIDn + h * HDn + hd] = o;
            ss[r] += o * o;
        }
    }
#pragma unroll
    for (int off = 1; off < 16; off <<= 1)
#pragma unroll
        for (int r = 0; r < 4; ++r) ss[r] += __shfl_xor(ss[r], off);
    if (l16 == 0) {
#pragma unroll
        for (int r = 0; r < 4; ++r)
            atomicAdd(&sumsq[b * Tn + tb + quad * 4 + r], ss[r]);
    }
}

// ---------------------------------------------------------------------------
// out_gemm (LN fused): xln = attn * lnw[k] * rsqrt(sumsq[bt]/512+eps) during
// the LDS stage; 64x64 dbuf MFMA.  (R4-verified)
// ---------------------------------------------------------------------------
__global__ __launch_bounds__(256, 2) void out_gemm(
    const float* __restrict__ attn, const float* __restrict__ sumsq,
    const float* __restrict__ lnwg, const bf16_t* __restrict__ Bw,
    float* __restrict__ out)
{
    const int n0 = blockIdx.x * 64;
    const int m0 = blockIdx.y * 64;
    const int tid = threadIdx.x;
    const int wv = tid >> 6, lane = tid & 63, l16 = lane & 15, quad = lane >> 4;
    __shared__ float lnw_s[HIDn];
    __shared__ float inv_s[64];
    __shared__ bf16_t As[2][64 * 72];
    __shared__ bf16_t Bs[2][64 * 72];

    for (int i = tid; i < HIDn; i += 256) lnw_s[i] = lnwg[i];
    if (tid < 64)
        inv_s[tid] = rsqrtf(sumsq[(m0 + tid) / 3] * (1.0f / HIDn) + 1e-3f);
    __syncthreads();

    const int rowA = tid >> 3, cA = tid & 7;
    const float inv0 = inv_s[rowA], inv1 = inv_s[rowA + 32];

    auto loadT = [&](int k0, float4 (&AF)[2][2], uint4 (&BR)[2], float4 (&LF)[2]) {
        LF[0] = *(const float4*)&lnw_s[k0 + cA * 8];
        LF[1] = *(const float4*)&lnw_s[k0 + cA * 8 + 4];
        AF[0][0] = *(const float4*)&attn[(size_t)(m0 + rowA) * HIDn + k0 + cA * 8];
        AF[0][1] = *(const float4*)&attn[(size_t)(m0 + rowA) * HIDn + k0 + cA * 8 + 4];
        AF[1][0] = *(const float4*)&attn[(size_t)(m0 + rowA + 32) * HIDn + k0 + cA * 8];
        AF[1][1] = *(const float4*)&attn[(size_t)(m0 + rowA + 32) * HIDn + k0 + cA * 8 + 4];
        BR[0] = *(const uint4*)&Bw[(size_t)(n0 + rowA) * HIDn + k0 + cA * 8];
        BR[1] = *(const uint4*)&Bw[(size_t)(n0 + rowA + 32) * HIDn + k0 + cA * 8];
    };
    auto storeT = [&](int buf, float4 (&AF)[2][2], uint4 (&BR)[2], float4 (&LF)[2]) {
#pragma unroll
        for (int j = 0; j < 2; ++j) {
            const float iv = j ? inv1 : inv0;
            bf16_t a8[8] = {(bf16_t)(AF[j][0].x * LF[0].x * iv), (bf16_t)(AF[j][0].y * LF[0].y * iv),
                            (bf16_t)(AF[j][0].z * LF[0].z * iv), (bf16_t)(AF[j][0].w * LF[0].w * iv),
                            (bf16_t)(AF[j][1].x * LF[1].x * iv), (bf16_t)(AF[j][1].y * LF[1].y * iv),
                            (bf16_t)(AF[j][1].z * LF[1].z * iv), (bf16_t)(AF[j][1].w * LF[1].w * iv)};
            *(uint4*)&As[buf][(rowA + j * 32) * 72 + cA * 8] = *(uint4*)a8;
            *(uint4*)&Bs[buf][(rowA + j * 32) * 72 + cA * 8] = BR[j];
        }
    };

    f32x4 acc[4];
#pragma unroll
    for (int i = 0; i < 4; ++i) acc[i] = f32x4{0.f, 0.f, 0.f, 0.f};

    float4 af0[2][2], af1[2][2], lf0[2], lf1[2];
    uint4 br0[2], br1[2];
    loadT(0, af0, br0, lf0);
    storeT(0, af0, br0, lf0);
    __syncthreads();

    auto compute = [&](int buf) {
#pragma unroll
        for (int ks = 0; ks < 2; ++ks) {
            bf16x8 a = *(const bf16x8*)&As[buf][(wv * 16 + l16) * 72 + ks * 32 + quad * 8];
#pragma unroll
            for (int nt = 0; nt < 4; ++nt) {
                bf16x8 bb = *(const bf16x8*)&Bs[buf][(nt * 16 + l16) * 72 + ks * 32 + quad * 8];
                acc[nt] = __builtin_amdgcn_mfma_f32_16x16x32_bf16(a, bb, acc[nt], 0, 0, 0);
            }
        }
    };

    for (int it = 0; it < 8; it += 2) {
        loadT((it + 1) * 64, af1, br1, lf1);
        compute(0);
        storeT(1, af1, br1, lf1);
        __syncthreads();
        const bool pf = (it + 2) < 8;
        if (pf) loadT((it + 2) * 64, af0, br0, lf0);
        compute(1);
        if (pf) storeT(0, af0, br0, lf0);
        __syncthreads();
    }
#pragma unroll
    for (int nt = 0; nt < 4; ++nt)
#pragma unroll
        for (int r = 0; r < 4; ++r) {
            const int m = m0 + wv * 16 + quad * 4 + r;
            const int n = n0 + nt * 16 + l16;
            out[(size_t)m * HIDn + n] = acc[nt][r];
        }
}

// ---------------------------------------------------------------------------
// Workspace: Qh@0 (6291456) | Kh@6291456 (12582912) | Vt@18874368 (12582912) |
// attn@31457280 (12582912) | Wb@44040192 (524288) | sumsq@44564480 (8192)
// ---------------------------------------------------------------------------
extern "C" void kernel_launch(void* const* d_in, const int* in_sizes, int n_in,
                              void* d_out, int out_size, void* d_ws, size_t ws_size,
                              hipStream_t stream)
{
    const float* q    = (const float*)d_in[0];
    const float* k    = (const float*)d_in[1];
    const float* v    = (const float*)d_in[2];
    const float* bias = (const float*)d_in[3];
    const int*   outcell = (const int*)d_in[5];
    const float* lw   = (const float*)d_in[6];
    const float* W    = (const float*)d_in[8];
    const float* lnw  = (const float*)d_in[9];
    float* out = (float*)d_out;

    char* ws = (char*)d_ws;
    bf16_t* Qh   = (bf16_t*)(ws);
    bf16_t* Kh   = (bf16_t*)(ws + 6291456);
    bf16_t* Vt   = (bf16_t*)(ws + 18874368);
    float*  attn = (float*)(ws + 31457280);
    bf16_t* Wb   = (bf16_t*)(ws + 44040192);
    float*  sumsq = (float*)(ws + 44564480);

    hipMemsetAsync(sumsq, 0, (Bn * Tn) * sizeof(float), stream);
    pack_qk<<<dim3(Bn * Sn), 192, 0, stream>>>(q, k, outcell, Qh, Kh);
    pack_v<<<dim3(Bn * Hn * 16), 256, 0, stream>>>(v, outcell, Vt);
    pack_w<<<dim3((HIDn * HIDn) / (256 * 8)), 256, 0, stream>>>(W, Wb);
    attn_kernel<<<dim3(Hn, Bn * (Tn / 64)), 256, 0, stream>>>(Qh, Kh, Vt, bias, lw, attn, sumsq);
    out_gemm<<<dim3(HIDn / 64, (Bn * Tn * Pn) / 64), 256, 0, stream>>>(attn, sumsq, lnw, Wb, out);
}